// Round 4
// baseline (89.693 us; speedup 1.0000x reference)
//
#include <hip/hip_runtime.h>
#include <cstdint>
#include <cstddef>

__device__ static const int   d_GOV[66] = {
  21,21, 9,12, 9,12,17,17,17,17,15,16,15,16, 8, 8,11, 8,14, 7,14, 7,
  13,13,13,13,15,15,15,15,10,10,10,10, 4, 3, 4, 3, 1, 1, 1, 1, 6, 6,
   6, 6,18,18,18,18, 0,20, 0,20,16,16,16,16, 0, 2,19, 2,10, 5,10, 5};
__device__ static const float d_NSYN[66] = {
  0,0, 2,2,2,2, 4,4,4,4, 6,6,6,6, 3,3,1,3, 2,2,2,2, 4,4,4,4,
  6,6,6,6, 6,6,6,6, 2,2,2,2, 4,4,4,4, 4,4,4,4, 4,4,4,4,
  3,2,3,2, 6,6,6,6, 3,2,1,2, 6,2,6,2};

__device__ __forceinline__ void gload_lds16(const void* g, void* l) {
  __builtin_amdgcn_global_load_lds(
      (const __attribute__((address_space(1))) void*)g,
      (__attribute__((address_space(3))) void*)l, 16, 0, 0);
}
__device__ __forceinline__ void gload_lds4(const void* g, void* l) {
  __builtin_amdgcn_global_load_lds(
      (const __attribute__((address_space(1))) void*)g,
      (__attribute__((address_space(3))) void*)l, 4, 0, 0);
}

// Kernel 1: 256 threads, 4 rounds x 64 positions, 4 threads cooperate per position.
// Single 16.9KB LDS buffer -> 8 blocks/CU (100% wave occupancy); coalesced
// global_load_lds staging; cross-block stagger hides stage->compute serialization.
__global__ __launch_bounds__(256, 4) void k_pos(
    const float* __restrict__ logits,
    const float* __restrict__ W,
    const int* __restrict__ tgt,
    const int* __restrict__ species,
    const unsigned char* __restrict__ mask,
    float* __restrict__ ws,
    int B, int L)
{
  const int tid  = threadIdx.x;
  const int lane = tid & 63;
  const int wave = tid >> 6;
  const int bpr  = L >> 8;                 // 256 positions per block, one row per block
  const int b    = blockIdx.x / bpr;

  __shared__ float sbuf[64 * 66];          // 16896 B staging buffer
  __shared__ float s_logw[66];
  __shared__ int   s_cnt[132];             // [0..65]=pred, [66..131]=tgt
  __shared__ float s_acc[5];

  if (tid < 66)  s_logw[tid] = __logf(fmaxf(W[species[b] * 66 + tid], 1e-8f));
  if (tid < 132) s_cnt[tid] = 0;
  if (tid < 5)   s_acc[tid] = 0.0f;

  const int p     = tid >> 2;              // position within round (0..63)
  const int q     = tid & 3;               // quarter
  const int kbase = q * 17;                // q: 0-16,17-33,34-50,51-65
  const int nk    = (q == 3) ? 15 : 17;

  float acc0 = 0.f, acc1 = 0.f, acc2 = 0.f, acc3 = 0.f, acc4 = 0.f;

  for (int r = 0; r < 4; ++r) {
    __syncthreads();                       // prev round done reading sbuf (r=0: init visible)

    const float* gbase = logits + ((size_t)blockIdx.x * 256 + r * 64) * 66;
    #pragma unroll
    for (int i = 0; i < 4; ++i)            // 1024 float4 = floats 0..4095
      gload_lds16(gbase + (size_t)(i * 256 + tid) * 4,
                  (char*)sbuf + (size_t)(i * 256 + wave * 64) * 16);
    if (wave == 0) {                       // tail floats 4096..4223, full-wave width-4
      gload_lds4(gbase + 4096 + lane, (char*)sbuf + 16384);
      gload_lds4(gbase + 4160 + lane, (char*)sbuf + 16640);
    }
    asm volatile("s_waitcnt vmcnt(0)" ::: "memory");
    __syncthreads();

    const int   pos  = blockIdx.x * 256 + r * 64 + p;
    const float* base = sbuf + p * 66 + kbase;

    // pass 1: local max/argmax (strict > keeps first index)
    float m = -3.4e38f; int ki = kbase;
    #pragma unroll
    for (int i = 0; i < 17; ++i) {
      if (i < nk) { float x = base[i]; if (x > m) { m = x; ki = kbase + i; } }
    }
    // 4-lane butterfly; ties -> smaller absolute index (np.argmax first-occurrence)
    #pragma unroll
    for (int d = 1; d <= 2; d <<= 1) {
      float om = __shfl_xor(m, d);
      int   oi = __shfl_xor(ki, d);
      if (om > m || (om == m && oi < ki)) { m = om; ki = oi; }
    }

    int tg = 0;
    if (q == 0) tg = tgt[pos];
    tg = __shfl(tg, lane & ~3);            // broadcast within 4-lane group

    // pass 2: sum of exps + x[tgt]
    float se = 0.f, xt = 0.f;
    #pragma unroll
    for (int i = 0; i < 17; ++i) {
      if (i < nk) {
        float x = base[i];
        se += __expf(x - m);
        if (kbase + i == tg) xt = x;
      }
    }
    #pragma unroll
    for (int d = 1; d <= 2; d <<= 1) {
      se += __shfl_xor(se, d);
      xt += __shfl_xor(xt, d);
    }

    if (q == 0) {
      const float mval = mask[pos] ? 1.0f : 0.0f;
      const float nll  = __logf(se) + m - xt;
      if (tg != 0) { acc0 += nll; acc1 += 1.0f; }
      acc2 += s_logw[ki] * mval;
      acc3 += s_logw[tg] * mval;
      acc4 += mval;
      if (mval != 0.0f) {
        if (ki >= 2) atomicAdd(&s_cnt[ki], 1);
        if (tg >= 2) atomicAdd(&s_cnt[66 + tg], 1);
      }
    }
  }

  // full-wave reduce of running sums (non-leader lanes carry 0)
  #pragma unroll
  for (int off = 32; off > 0; off >>= 1) {
    acc0 += __shfl_xor(acc0, off);
    acc1 += __shfl_xor(acc1, off);
    acc2 += __shfl_xor(acc2, off);
    acc3 += __shfl_xor(acc3, off);
    acc4 += __shfl_xor(acc4, off);
  }
  if (lane == 0) {
    atomicAdd(&s_acc[0], acc0);
    atomicAdd(&s_acc[1], acc1);
    atomicAdd(&s_acc[2], acc2);
    atomicAdd(&s_acc[3], acc3);
    atomicAdd(&s_acc[4], acc4);
  }
  __syncthreads();

  int* wsi = (int*)ws;
  const int off_slp = 2, off_slt = 2 + B, off_mc = 2 + 2 * B, off_cp = 2 + 3 * B;
  const int off_ct = off_cp + B * 66;
  if (tid == 0) {
    atomicAdd(&ws[0], s_acc[0]);
    atomicAdd(&ws[1], s_acc[1]);
    atomicAdd(&ws[off_slp + b], s_acc[2]);
    atomicAdd(&ws[off_slt + b], s_acc[3]);
    atomicAdd(&ws[off_mc + b], s_acc[4]);
  }
  if (tid < 66)       atomicAdd(&wsi[off_cp + b * 66 + tid], s_cnt[tid]);
  else if (tid < 132) atomicAdd(&wsi[off_ct + b * 66 + (tid - 66)], s_cnt[tid]);
}

// Kernel 2: per-row CAI + RSCU-KL, codon-parallel. Grid: B blocks x 128 threads.
__global__ __launch_bounds__(128) void k_row(
    const float* __restrict__ refd,
    const int* __restrict__ species,
    float* __restrict__ ws,
    int B)
{
  const int b    = blockIdx.x;
  const int tid  = threadIdx.x;
  const int lane = tid & 63;
  const int wave = tid >> 6;
  const int off_slp = 2, off_slt = 2 + B, off_mc = 2 + 2 * B, off_cp = 2 + 3 * B;
  const int off_ct = off_cp + B * 66;
  const int off_res = off_ct + B * 66;
  const int* wsi = (const int*)ws;

  __shared__ float gp[24], gt[24];
  __shared__ float red[8];
  if (tid < 24) { gp[tid] = 0.0f; gt[tid] = 0.0f; }
  __syncthreads();

  float cp = 0.0f, ct = 0.0f, nsyn = 0.0f, ref = 0.0f;
  int gov = 22;
  if (tid < 66) {
    cp = (float)wsi[off_cp + b * 66 + tid];
    ct = (float)wsi[off_ct + b * 66 + tid];
    gov  = d_GOV[tid];
    nsyn = d_NSYN[tid];
    ref  = refd[species[b] * 66 + tid];
    atomicAdd(&gp[gov], cp);   // integer-valued floats: order-independent exact
    atomicAdd(&gt[gov], ct);
  }
  __syncthreads();

  float rp = 0.0f, rt = 0.0f;
  if (tid < 66) {
    float g1 = gp[gov]; rp = (g1 > 0.0f) ? cp * nsyn / g1 : 0.0f;
    float g2 = gt[gov]; rt = (g2 > 0.0f) ? ct * nsyn / g2 : 0.0f;
  }
  float pp = (tid < 66) ? (rp + 1e-8f) : 0.0f;
  float tp = (tid < 66) ? (0.7f * rt + 0.3f * ref + 1e-8f) : 0.0f;
  #pragma unroll
  for (int off = 32; off > 0; off >>= 1) {
    pp += __shfl_xor(pp, off);
    tp += __shfl_xor(tp, off);
  }
  if (lane == 0) { red[wave * 2] = pp; red[wave * 2 + 1] = tp; }
  __syncthreads();
  const float psum = red[0] + red[2];
  const float tsum = red[1] + red[3];

  float kl = 0.0f;
  if (tid < 66) {
    float pv = (rp + 1e-8f) / psum;
    float tv = (0.7f * rt + 0.3f * ref + 1e-8f) / tsum;
    kl = tv * __logf(tv / pv);
  }
  #pragma unroll
  for (int off = 32; off > 0; off >>= 1) kl += __shfl_xor(kl, off);
  if (lane == 0) red[4 + wave] = kl;
  __syncthreads();

  if (tid == 0) {
    float klt = red[4] + red[5];
    float mc    = fmaxf(ws[off_mc + b], 1.0f);
    float cai_p = __expf(ws[off_slp + b] / mc);
    float cai_t = __expf(ws[off_slt + b] / mc);
    float cai_l = fmaxf(cai_t - cai_p, 0.0f);
    ws[off_res + b] = 0.4f * cai_l + 0.3f * klt;
  }
}

// Kernel 3: final scalar. 1 block, B threads.
__global__ __launch_bounds__(128) void k_sum(
    const float* __restrict__ ws,
    float* __restrict__ out, int B)
{
  const int b = threadIdx.x;
  const int lane = b & 63, wave = b >> 6;
  const int off_res = 2 + 3 * B + 2 * B * 66;
  float r = (b < B) ? ws[off_res + b] : 0.0f;
  #pragma unroll
  for (int off = 32; off > 0; off >>= 1) r += __shfl_xor(r, off);
  __shared__ float sr[2];
  if (lane == 0) sr[wave] = r;
  __syncthreads();
  if (b == 0) {
    float ce = ws[0] / fmaxf(ws[1], 1.0f);
    out[0] = ce + (sr[0] + sr[1]) / (float)B;
  }
}

extern "C" void kernel_launch(void* const* d_in, const int* in_sizes, int n_in,
                              void* d_out, int out_size, void* d_ws, size_t ws_size,
                              hipStream_t stream) {
  const float* logits  = (const float*)d_in[0];
  const float* W       = (const float*)d_in[1];
  const float* refd    = (const float*)d_in[2];
  const int*   tgt     = (const int*)d_in[3];
  // d_in[4] = aa_ids: unused by the reference
  const int*   species = (const int*)d_in[5];
  const unsigned char* mask = (const unsigned char*)d_in[6];  // numpy bool = 1 byte
  float* out = (float*)d_out;
  float* ws  = (float*)d_ws;

  const int B = in_sizes[5];
  const int L = in_sizes[3] / B;       // 4096
  const int nblk = (B * L) >> 8;       // 256 positions per block

  const int ws_words = 2 + 3 * B + 2 * B * 66 + B;
  hipMemsetAsync(d_ws, 0, (size_t)ws_words * 4, stream);

  hipLaunchKernelGGL(k_pos, dim3(nblk), dim3(256), 0, stream,
                     logits, W, tgt, species, mask, ws, B, L);
  hipLaunchKernelGGL(k_row, dim3(B), dim3(128), 0, stream,
                     refd, species, ws, B);
  hipLaunchKernelGGL(k_sum, dim3(1), dim3(128), 0, stream,
                     ws, out, B);
}

// Round 5
// 83.873 us; speedup vs baseline: 1.0694x; 1.0694x over previous
//
#include <hip/hip_runtime.h>
#include <cstdint>
#include <cstddef>

__device__ static const int   d_GOV[66] = {
  21,21, 9,12, 9,12,17,17,17,17,15,16,15,16, 8, 8,11, 8,14, 7,14, 7,
  13,13,13,13,15,15,15,15,10,10,10,10, 4, 3, 4, 3, 1, 1, 1, 1, 6, 6,
   6, 6,18,18,18,18, 0,20, 0,20,16,16,16,16, 0, 2,19, 2,10, 5,10, 5};
__device__ static const float d_NSYN[66] = {
  0,0, 2,2,2,2, 4,4,4,4, 6,6,6,6, 3,3,1,3, 2,2,2,2, 4,4,4,4,
  6,6,6,6, 6,6,6,6, 2,2,2,2, 4,4,4,4, 4,4,4,4, 4,4,4,4,
  3,2,3,2, 6,6,6,6, 3,2,1,2, 6,2,6,2};

__device__ __forceinline__ void gload_lds16(const void* g, void* l) {
  __builtin_amdgcn_global_load_lds(
      (const __attribute__((address_space(1))) void*)g,
      (__attribute__((address_space(3))) void*)l, 16, 0, 0);
}

// k_pos: 1-wave (64-thread) blocks; 8 rounds x 64 positions; per-wave
// double-buffered global_load_lds pipeline; no barriers in steady state.
// All waits are conservative vmcnt(0) drains placed AFTER issuing the next
// prefetch, so correctness never depends on outstanding-load counting.
__global__ __launch_bounds__(64) void k_pos(
    const float* __restrict__ logits,
    const float* __restrict__ W,
    const int* __restrict__ tgt,
    const int* __restrict__ species,
    const unsigned char* __restrict__ mask,
    float* __restrict__ ws,
    int B, int L)
{
  const int lane = threadIdx.x;            // 0..63
  const int blk  = blockIdx.x;
  const int bpr  = L >> 9;                 // 512 positions per block
  const int b    = blk / bpr;
  const size_t base_pos = (size_t)blk * 512;

  __shared__ float sbuf[2][4352];          // 2 x 17408 B (4224 used + 512 B pad)
  __shared__ float s_logw[66];
  __shared__ int   s_cnt[132];             // [0..65]=pred, [66..131]=tgt

  // ---- prologue: all global scalar state loaded & drained up front ----
  {
    const int s = species[b];
    s_logw[lane] = __logf(fmaxf(W[s * 66 + lane], 1e-8f));
    if (lane < 2) s_logw[64 + lane] = __logf(fmaxf(W[s * 66 + 64 + lane], 1e-8f));
  }
  s_cnt[lane] = 0; s_cnt[64 + lane] = 0;
  if (lane < 4) s_cnt[128 + lane] = 0;

  int tg_[8]; float mk_[8];
  #pragma unroll
  for (int r = 0; r < 8; ++r) {
    const size_t pos = base_pos + r * 64 + lane;
    tg_[r] = tgt[pos];
    mk_[r] = mask[pos] ? 1.0f : 0.0f;
  }
  __syncthreads();                          // LDS init visible (1 wave, cheap)

  // stage round 0 into buf0
  {
    const float* gb = logits + base_pos * 66;
    #pragma unroll
    for (int i = 0; i < 16; ++i)
      gload_lds16(gb + (size_t)(i * 64 + lane) * 4, (char*)sbuf[0] + (size_t)i * 1024);
    if (lane < 32)
      gload_lds16(gb + (size_t)(4096 + lane * 4), (char*)sbuf[0] + 16384);
  }
  asm volatile("s_waitcnt vmcnt(0) lgkmcnt(0)" ::: "memory");

  float acc0 = 0.f, acc1 = 0.f, acc2 = 0.f, acc3 = 0.f, acc4 = 0.f;

  #pragma unroll
  for (int r = 0; r < 8; ++r) {
    // issue next round's prefetch into the other buffer (overlaps compute)
    if (r < 7) {
      const float* gb = logits + (base_pos + (size_t)(r + 1) * 64) * 66;
      char* dst = (char*)sbuf[(r + 1) & 1];
      #pragma unroll
      for (int i = 0; i < 16; ++i)
        gload_lds16(gb + (size_t)(i * 64 + lane) * 4, dst + (size_t)i * 1024);
      if (lane < 32)
        gload_lds16(gb + (size_t)(4096 + lane * 4), dst + 16384);
    }

    // compute current buffer: 1 thread per position, conflict-free b64 reads
    const float* row = &sbuf[r & 1][lane * 66];
    float v[66];
    #pragma unroll
    for (int k = 0; k < 33; ++k) {
      float2 t = ((const float2*)row)[k];
      v[2 * k] = t.x; v[2 * k + 1] = t.y;
    }
    float m0 = v[0]; int p0 = 0;
    #pragma unroll
    for (int k = 1; k < 33; ++k) { if (v[k] > m0) { m0 = v[k]; p0 = k; } }
    float m1 = v[33]; int p1 = 33;
    #pragma unroll
    for (int k = 34; k < 66; ++k) { if (v[k] > m1) { m1 = v[k]; p1 = k; } }
    float mx = m0; int pr = p0;
    if (m1 > m0) { mx = m1; pr = p1; }     // strict >: first-occurrence tie-break

    float se0 = 0.f, se1 = 0.f, se2 = 0.f, se3 = 0.f;
    #pragma unroll
    for (int k = 0; k < 64; k += 4) {
      se0 += __expf(v[k]     - mx);
      se1 += __expf(v[k + 1] - mx);
      se2 += __expf(v[k + 2] - mx);
      se3 += __expf(v[k + 3] - mx);
    }
    se0 += __expf(v[64] - mx);
    se1 += __expf(v[65] - mx);
    const float se = (se0 + se1) + (se2 + se3);

    const int   tg   = tg_[r];
    const float mval = mk_[r];
    const float xt   = row[tg];            // single LDS gather
    const float nll  = __logf(se) + mx - xt;
    if (tg != 0) { acc0 += nll; acc1 += 1.0f; }
    acc2 += s_logw[pr] * mval;
    acc3 += s_logw[tg] * mval;
    acc4 += mval;
    if (mval != 0.0f) {
      if (pr >= 2) atomicAdd(&s_cnt[pr], 1);
      if (tg >= 2) atomicAdd(&s_cnt[66 + tg], 1);
    }

    // drain this round's prefetch (had full compute phase to complete)
    asm volatile("s_waitcnt vmcnt(0) lgkmcnt(0)" ::: "memory");
  }

  // wave reduction + global flush
  #pragma unroll
  for (int off = 32; off > 0; off >>= 1) {
    acc0 += __shfl_xor(acc0, off);
    acc1 += __shfl_xor(acc1, off);
    acc2 += __shfl_xor(acc2, off);
    acc3 += __shfl_xor(acc3, off);
    acc4 += __shfl_xor(acc4, off);
  }
  int* wsi = (int*)ws;
  const int off_slp = 2, off_slt = 2 + B, off_mc = 2 + 2 * B, off_cp = 2 + 3 * B;
  const int off_ct = off_cp + B * 66;
  if (lane == 0) {
    atomicAdd(&ws[0], acc0);
    atomicAdd(&ws[1], acc1);
    atomicAdd(&ws[off_slp + b], acc2);
    atomicAdd(&ws[off_slt + b], acc3);
    atomicAdd(&ws[off_mc + b], acc4);
  }
  __syncthreads();                          // s_cnt atomics done
  for (int j = lane; j < 132; j += 64) {
    const int val = s_cnt[j];
    if (val != 0) {
      if (j < 66) atomicAdd(&wsi[off_cp + b * 66 + j], val);
      else        atomicAdd(&wsi[off_ct + b * 66 + (j - 66)], val);
    }
  }
}

// Kernel 2: per-row CAI + RSCU-KL, codon-parallel. Grid: B blocks x 128 threads.
__global__ __launch_bounds__(128) void k_row(
    const float* __restrict__ refd,
    const int* __restrict__ species,
    float* __restrict__ ws,
    int B)
{
  const int b    = blockIdx.x;
  const int tid  = threadIdx.x;
  const int lane = tid & 63;
  const int wave = tid >> 6;
  const int off_slp = 2, off_slt = 2 + B, off_mc = 2 + 2 * B, off_cp = 2 + 3 * B;
  const int off_ct = off_cp + B * 66;
  const int off_res = off_ct + B * 66;
  const int* wsi = (const int*)ws;

  __shared__ float gp[24], gt[24];
  __shared__ float red[8];
  if (tid < 24) { gp[tid] = 0.0f; gt[tid] = 0.0f; }
  __syncthreads();

  float cp = 0.0f, ct = 0.0f, nsyn = 0.0f, ref = 0.0f;
  int gov = 22;
  if (tid < 66) {
    cp = (float)wsi[off_cp + b * 66 + tid];
    ct = (float)wsi[off_ct + b * 66 + tid];
    gov  = d_GOV[tid];
    nsyn = d_NSYN[tid];
    ref  = refd[species[b] * 66 + tid];
    atomicAdd(&gp[gov], cp);   // integer-valued floats: order-independent exact
    atomicAdd(&gt[gov], ct);
  }
  __syncthreads();

  float rp = 0.0f, rt = 0.0f;
  if (tid < 66) {
    float g1 = gp[gov]; rp = (g1 > 0.0f) ? cp * nsyn / g1 : 0.0f;
    float g2 = gt[gov]; rt = (g2 > 0.0f) ? ct * nsyn / g2 : 0.0f;
  }
  float pp = (tid < 66) ? (rp + 1e-8f) : 0.0f;
  float tp = (tid < 66) ? (0.7f * rt + 0.3f * ref + 1e-8f) : 0.0f;
  #pragma unroll
  for (int off = 32; off > 0; off >>= 1) {
    pp += __shfl_xor(pp, off);
    tp += __shfl_xor(tp, off);
  }
  if (lane == 0) { red[wave * 2] = pp; red[wave * 2 + 1] = tp; }
  __syncthreads();
  const float psum = red[0] + red[2];
  const float tsum = red[1] + red[3];

  float kl = 0.0f;
  if (tid < 66) {
    float pv = (rp + 1e-8f) / psum;
    float tv = (0.7f * rt + 0.3f * ref + 1e-8f) / tsum;
    kl = tv * __logf(tv / pv);
  }
  #pragma unroll
  for (int off = 32; off > 0; off >>= 1) kl += __shfl_xor(kl, off);
  if (lane == 0) red[4 + wave] = kl;
  __syncthreads();

  if (tid == 0) {
    float klt = red[4] + red[5];
    float mc    = fmaxf(ws[off_mc + b], 1.0f);
    float cai_p = __expf(ws[off_slp + b] / mc);
    float cai_t = __expf(ws[off_slt + b] / mc);
    float cai_l = fmaxf(cai_t - cai_p, 0.0f);
    ws[off_res + b] = 0.4f * cai_l + 0.3f * klt;
  }
}

// Kernel 3: final scalar. 1 block, B threads.
__global__ __launch_bounds__(128) void k_sum(
    const float* __restrict__ ws,
    float* __restrict__ out, int B)
{
  const int b = threadIdx.x;
  const int lane = b & 63, wave = b >> 6;
  const int off_res = 2 + 3 * B + 2 * B * 66;
  float r = (b < B) ? ws[off_res + b] : 0.0f;
  #pragma unroll
  for (int off = 32; off > 0; off >>= 1) r += __shfl_xor(r, off);
  __shared__ float sr[2];
  if (lane == 0) sr[wave] = r;
  __syncthreads();
  if (b == 0) {
    float ce = ws[0] / fmaxf(ws[1], 1.0f);
    out[0] = ce + (sr[0] + sr[1]) / (float)B;
  }
}

extern "C" void kernel_launch(void* const* d_in, const int* in_sizes, int n_in,
                              void* d_out, int out_size, void* d_ws, size_t ws_size,
                              hipStream_t stream) {
  const float* logits  = (const float*)d_in[0];
  const float* W       = (const float*)d_in[1];
  const float* refd    = (const float*)d_in[2];
  const int*   tgt     = (const int*)d_in[3];
  // d_in[4] = aa_ids: unused by the reference
  const int*   species = (const int*)d_in[5];
  const unsigned char* mask = (const unsigned char*)d_in[6];  // numpy bool = 1 byte
  float* out = (float*)d_out;
  float* ws  = (float*)d_ws;

  const int B = in_sizes[5];
  const int L = in_sizes[3] / B;       // 4096
  const int nblk = (B * L) >> 9;       // 512 positions per 1-wave block

  const int ws_words = 2 + 3 * B + 2 * B * 66 + B;
  hipMemsetAsync(d_ws, 0, (size_t)ws_words * 4, stream);

  hipLaunchKernelGGL(k_pos, dim3(nblk), dim3(64), 0, stream,
                     logits, W, tgt, species, mask, ws, B, L);
  hipLaunchKernelGGL(k_row, dim3(B), dim3(128), 0, stream,
                     refd, species, ws, B);
  hipLaunchKernelGGL(k_sum, dim3(1), dim3(128), 0, stream,
                     ws, out, B);
}